// Round 4
// baseline (253.915 us; speedup 1.0000x reference)
//
#include <hip/hip_runtime.h>
#include <hip/hip_bf16.h>

// out = v + 0.5*mask*(softmax_m(mem@v^T - 0.5*||mem||^2)^T @ mem - v)
//  k_prep  : memories f32 -> bf16 (memA) + row sumsq (msq); v -> bf16 (vbf)
//  k_stage1: 256 WGs = 128 m-splits x 2 b-tiles. 8 chunks of 64 m, double-
//            buffered global_load_lds A staging, in-LDS transpose -> Tb,
//            per-wave 32-b (2 col-fragments) online softmax, PV with acc in
//            [d][b] orientation (lane-uniform rescale), defer-max (THR=8),
//            LDS-staged contiguous part_o[s][b][d] epilogue.
//  k_out   : fused per-b stat combine + partial reduction + epilogue

#define D_DIM 256
#define B_DIM 512
#define M_TOT 65536
#define NSPLIT 128     // m-splits; 512 m per split
#define CHUNK 64
#define NCHUNK 8

typedef __attribute__((ext_vector_type(4))) float f32x4;
typedef __attribute__((ext_vector_type(8))) short s16x8;
typedef __attribute__((ext_vector_type(2))) unsigned int u32x2;
typedef __attribute__((ext_vector_type(4))) unsigned int u32x4;

__device__ __forceinline__ unsigned short bf16rn(float f) {
  unsigned x = __builtin_bit_cast(unsigned, f);
  x += 0x7fffu + ((x >> 16) & 1u);
  return (unsigned short)(x >> 16);
}
__device__ __forceinline__ unsigned pk2(float a, float b) {
  return (unsigned)bf16rn(a) | ((unsigned)bf16rn(b) << 16);
}
__device__ __forceinline__ float bf2f(unsigned short u) {
  return __builtin_bit_cast(float, ((unsigned)u) << 16);
}

#define TSWZ(d) ((((d) ^ ((d) >> 3)) & 7) << 4)

// ---------------- kernel 0: prep ----------------
__global__ __launch_bounds__(512) void k_prep(const float* __restrict__ memg,
                                              const float* __restrict__ v,
                                              unsigned short* __restrict__ memA,
                                              unsigned short* __restrict__ vbf,
                                              float* __restrict__ msq) {
  const int wg = (int)blockIdx.x;
  const int tid = (int)threadIdx.x;
  const int w = tid >> 6, lane = tid & 63;
  if (wg < 256) {
    size_t m0 = (size_t)wg * 256 + w * 32;
#pragma unroll 4
    for (int i = 0; i < 32; ++i) {
      size_t m = m0 + i;
      f32x4 f = *reinterpret_cast<const f32x4*>(memg + m * 256 + lane * 4);
      u32x2 p;
      p[0] = pk2(f[0], f[1]);
      p[1] = pk2(f[2], f[3]);
      *reinterpret_cast<u32x2*>(memA + m * 256 + lane * 4) = p;
      float sq = f[0] * f[0] + f[1] * f[1] + f[2] * f[2] + f[3] * f[3];
#pragma unroll
      for (int s2 = 32; s2; s2 >>= 1) sq += __shfl_xor(sq, s2);
      if (lane == 0) msq[m] = sq;
    }
  } else {
    size_t base = (size_t)(wg - 256) * 8192 + (size_t)tid * 16;
#pragma unroll
    for (int i = 0; i < 4; ++i) {
      f32x4 f = *reinterpret_cast<const f32x4*>(v + base + i * 4);
      u32x2 p;
      p[0] = pk2(f[0], f[1]);
      p[1] = pk2(f[2], f[3]);
      *reinterpret_cast<u32x2*>(vbf + base + i * 4) = p;
    }
  }
}

// ---------------- softmax + PA-shuffle macros ----------------
#define SOFTMAX_UPD(S_, rm_, rs_, acc_)                                        \
  {                                                                            \
    float mx = S_[0][0];                                                       \
    _Pragma("unroll") for (int rf_ = 0; rf_ < 4; ++rf_)                        \
        _Pragma("unroll") for (int r_ = 0; r_ < 4; ++r_)                       \
            mx = fmaxf(mx, S_[rf_][r_]);                                       \
    mx = fmaxf(mx, __shfl_xor(mx, 16));                                        \
    mx = fmaxf(mx, __shfl_xor(mx, 32));                                        \
    if (!__all(mx <= rm_ + 8.0f)) {                                            \
      float nm = fmaxf(rm_, mx);                                               \
      float al = __expf(rm_ - nm);                                             \
      rm_ = nm;                                                                \
      rs_ *= al;                                                               \
      _Pragma("unroll") for (int n_ = 0; n_ < 16; ++n_) acc_[n_] = acc_[n_] * al; \
    }                                                                          \
    float ls = 0.f;                                                            \
    _Pragma("unroll") for (int rf_ = 0; rf_ < 4; ++rf_)                        \
        _Pragma("unroll") for (int r_ = 0; r_ < 4; ++r_) {                     \
      float p_ = __expf(S_[rf_][r_] - rm_);                                    \
      S_[rf_][r_] = p_;                                                        \
      ls += p_;                                                                \
    }                                                                          \
    ls += __shfl_xor(ls, 16);                                                  \
    ls += __shfl_xor(ls, 32);                                                  \
    rs_ += ls;                                                                 \
  }

#define MAKE_PA(S_, kk_, pa_)                                                  \
  {                                                                            \
    unsigned q00 = pk2(S_[2 * kk_][0], S_[2 * kk_][1]);                        \
    unsigned q01 = pk2(S_[2 * kk_][2], S_[2 * kk_][3]);                        \
    unsigned q10 = pk2(S_[2 * kk_ + 1][0], S_[2 * kk_ + 1][1]);                \
    unsigned q11 = pk2(S_[2 * kk_ + 1][2], S_[2 * kk_ + 1][3]);                \
    int srcA = ((lane & 16) >> 3) * 16 + c;                                    \
    int srcB = srcA + 16;                                                      \
    unsigned a0 = (unsigned)__shfl((int)q00, srcA);                            \
    unsigned b0 = (unsigned)__shfl((int)q10, srcA);                            \
    unsigned a1 = (unsigned)__shfl((int)q01, srcA);                            \
    unsigned b1 = (unsigned)__shfl((int)q11, srcA);                            \
    unsigned a2 = (unsigned)__shfl((int)q00, srcB);                            \
    unsigned b2 = (unsigned)__shfl((int)q10, srcB);                            \
    unsigned a3 = (unsigned)__shfl((int)q01, srcB);                            \
    unsigned b3 = (unsigned)__shfl((int)q11, srcB);                            \
    bool hi = lane >= 32;                                                      \
    u32x4 wv;                                                                  \
    wv[0] = hi ? b0 : a0;                                                      \
    wv[1] = hi ? b1 : a1;                                                      \
    wv[2] = hi ? b2 : a2;                                                      \
    wv[3] = hi ? b3 : a3;                                                      \
    pa_ = __builtin_bit_cast(s16x8, wv);                                       \
  }

// ---------------- kernel 1: split-M flash ----------------
__global__ __launch_bounds__(512, 2) void k_stage1(
    const unsigned short* __restrict__ memA, const unsigned short* __restrict__ vbf,
    const float* __restrict__ msq, unsigned short* __restrict__ part_o,
    float* __restrict__ part_m, float* __restrict__ part_l) {
  __shared__ __align__(16) char lds[98304];  // Ab0 32K | Ab1 32K | Tb 32K
  char* const Ab0 = lds;
  char* const Ab1 = lds + 32768;
  char* const Tb = lds + 65536;

  const int tid = (int)threadIdx.x;
  const int w = tid >> 6;
  const int lane = tid & 63;
  const int g = lane >> 4;
  const int c = lane & 15;

  // XCD swizzle: the 2 b-tiles of an m-split land on the same XCD.
  const int bid = (int)blockIdx.x;
  const int swz = (bid & 7) * 32 + (bid >> 3);
  const int s = swz >> 1;       // m-split 0..127
  const int btile = swz & 1;    // b-tile 0..1
  const int mbase = s * 512;
  const int bw = btile * 256 + w * 32;

  const char* memAc = (const char*)memA;
  const int mrow = w * 2 + (lane >> 5);
  const size_t a_src0 = ((size_t)mbase + (size_t)mrow) * 512 +
                        (size_t)(((lane & 31) * 16) ^ ((mrow & 7) << 4));

#define STAGE(bufp, t)                                                          \
  do {                                                                          \
    _Pragma("unroll") for (int i_ = 0; i_ < 4; ++i_) {                          \
      __builtin_amdgcn_global_load_lds(                                         \
          (const __attribute__((address_space(1))) void*)(memAc + a_src0 +      \
              (size_t)(t) * 32768 + (size_t)i_ * 8192),                         \
          (__attribute__((address_space(3))) void*)((bufp) + i_ * 8192 + w * 1024), \
          16, 0, 0);                                                            \
    }                                                                           \
  } while (0)

  f32x4 acc0[16], acc1[16];
#pragma unroll
  for (int n = 0; n < 16; ++n) { acc0[n] = (f32x4)0.0f; acc1[n] = (f32x4)0.0f; }
  float rm0 = -__builtin_inff(), rs0 = 0.f;
  float rm1 = -__builtin_inff(), rs1 = 0.f;

  s16x8 vr0[8], vr1[8];

  STAGE(Ab0, 0);
#pragma unroll
  for (int k = 0; k < 8; ++k) {
    vr0[k] = *reinterpret_cast<const s16x8*>(vbf + (size_t)(bw + c) * 256 + k * 32 + g * 8);
    vr1[k] = *reinterpret_cast<const s16x8*>(vbf + (size_t)(bw + 16 + c) * 256 + k * 32 + g * 8);
  }

  asm volatile("s_waitcnt vmcnt(0)" ::: "memory");
  __builtin_amdgcn_s_barrier();
  asm volatile("" ::: "memory");

  const int db = tid & 31;
  const int mb = tid >> 5;
  const int d0 = db * 8, mm0 = mb * 4;

  for (int t = 0; t < NCHUNK; ++t) {
    char* Abc = (t & 1) ? Ab1 : Ab0;
    char* Abn = (t & 1) ? Ab0 : Ab1;
    if (t < NCHUNK - 1) STAGE(Abn, t + 1);

    // ---- transpose Ab[cur] -> Tb ----
    {
      u32x4 r0 = *reinterpret_cast<const u32x4*>(Abc + (((mm0 + 0) * 512 + d0 * 2) ^ (((mm0 + 0) & 7) << 4)));
      u32x4 r1 = *reinterpret_cast<const u32x4*>(Abc + (((mm0 + 1) * 512 + d0 * 2) ^ (((mm0 + 1) & 7) << 4)));
      u32x4 r2 = *reinterpret_cast<const u32x4*>(Abc + (((mm0 + 2) * 512 + d0 * 2) ^ (((mm0 + 2) & 7) << 4)));
      u32x4 r3 = *reinterpret_cast<const u32x4*>(Abc + (((mm0 + 3) * 512 + d0 * 2) ^ (((mm0 + 3) & 7) << 4)));
#pragma unroll
      for (int dd = 0; dd < 8; ++dd) {
        int sh = (dd & 1) * 16;
        unsigned h0 = (r0[dd >> 1] >> sh) & 0xffffu;
        unsigned h1 = (r1[dd >> 1] >> sh) & 0xffffu;
        unsigned h2 = (r2[dd >> 1] >> sh) & 0xffffu;
        unsigned h3 = (r3[dd >> 1] >> sh) & 0xffffu;
        u32x2 pw;
        pw[0] = h0 | (h1 << 16);
        pw[1] = h2 | (h3 << 16);
        int d = d0 + dd;
        *reinterpret_cast<u32x2*>(Tb + ((d * 128 + mm0 * 2) ^ TSWZ(d))) = pw;
      }
    }
    asm volatile("s_waitcnt lgkmcnt(0)" ::: "memory");
    __builtin_amdgcn_s_barrier();
    asm volatile("" ::: "memory");

    const int mc = mbase + t * 64;

    // ---- QK^T (swapped): S[m-frag][b=c], two column-fragments ----
    f32x4 S0[4], S1[4];
#pragma unroll
    for (int rf = 0; rf < 4; ++rf) { S0[rf] = (f32x4)0.0f; S1[rf] = (f32x4)0.0f; }
    __builtin_amdgcn_s_setprio(1);
#pragma unroll
    for (int k = 0; k < 8; ++k) {
#pragma unroll
      for (int rf = 0; rf < 4; ++rf) {
        s16x8 a = *reinterpret_cast<const s16x8*>(
            Abc + (((rf * 16 + c) * 512 + k * 64 + g * 16) ^ ((c & 7) << 4)));
        S0[rf] = __builtin_amdgcn_mfma_f32_16x16x32_bf16(a, vr0[k], S0[rf], 0, 0, 0);
        S1[rf] = __builtin_amdgcn_mfma_f32_16x16x32_bf16(a, vr1[k], S1[rf], 0, 0, 0);
      }
    }
    __builtin_amdgcn_s_setprio(0);
    // bias: row m = rf*16 + 4g + r
#pragma unroll
    for (int rf = 0; rf < 4; ++rf) {
      f32x4 q = *reinterpret_cast<const f32x4*>(msq + mc + rf * 16 + g * 4);
#pragma unroll
      for (int r = 0; r < 4; ++r) { S0[rf][r] -= 0.5f * q[r]; S1[rf][r] -= 0.5f * q[r]; }
    }

    // ---- online softmax (acc cols are b=c -> lane-uniform rescale) ----
    SOFTMAX_UPD(S0, rm0, rs0, acc0);
    SOFTMAX_UPD(S1, rm1, rs1, acc1);

    // ---- PV: acc[d][b] += memT @ P  (A = Tb fragment, B = P^T shuffle) ----
#pragma unroll
    for (int kk = 0; kk < 2; ++kk) {
      s16x8 pa0, pa1;
      MAKE_PA(S0, kk, pa0);
      MAKE_PA(S1, kk, pa1);
      __builtin_amdgcn_s_setprio(1);
#pragma unroll
      for (int n = 0; n < 16; ++n) {
        int d = n * 16 + c;
        s16x8 bm = *reinterpret_cast<const s16x8*>(Tb + ((d * 128 + kk * 64 + g * 16) ^ TSWZ(d)));
        acc0[n] = __builtin_amdgcn_mfma_f32_16x16x32_bf16(bm, pa0, acc0[n], 0, 0, 0);
        acc1[n] = __builtin_amdgcn_mfma_f32_16x16x32_bf16(bm, pa1, acc1[n], 0, 0, 0);
      }
      __builtin_amdgcn_s_setprio(0);
    }

    asm volatile("s_waitcnt vmcnt(0) lgkmcnt(0)" ::: "memory");
    __builtin_amdgcn_s_barrier();
    asm volatile("" ::: "memory");
  }

  // ---- stats: per-b (b = bw + cf*16 + c) ----
  if (g == 0) {
    int b0s = bw + c;
    part_m[(size_t)b0s * NSPLIT + s] = rm0;
    part_l[(size_t)b0s * NSPLIT + s] = rs0;
    part_m[(size_t)(b0s + 16) * NSPLIT + s] = rm1;
    part_l[(size_t)(b0s + 16) * NSPLIT + s] = rs1;
  }

  // ---- epilogue: acc lane layout (b = bw+cf*16+c, d = n*16+4g+r) ----
  {
    char* ep = lds;
#pragma unroll
    for (int cf = 0; cf < 2; ++cf) {
      __syncthreads();
#pragma unroll
      for (int n = 0; n < 16; ++n) {
        u32x2 pw;
        if (cf == 0) { pw[0] = pk2(acc0[n][0], acc0[n][1]); pw[1] = pk2(acc0[n][2], acc0[n][3]); }
        else         { pw[0] = pk2(acc1[n][0], acc1[n][1]); pw[1] = pk2(acc1[n][2], acc1[n][3]); }
        *reinterpret_cast<u32x2*>(ep + w * 8448 + c * 528 + (n * 16 + 4 * g) * 2) = pw;
      }
      __syncthreads();
      int row = tid >> 2, q = tid & 3;
      size_t bglob = (size_t)btile * 256 + (size_t)(row >> 4) * 32 + (size_t)cf * 16 + (row & 15);
      char* dst = (char*)part_o + ((size_t)s * 512 + bglob) * 512 + q * 128;
      const char* srcp = ep + (row >> 4) * 8448 + (row & 15) * 528 + q * 128;
#pragma unroll
      for (int i = 0; i < 8; ++i)
        *reinterpret_cast<u32x4*>(dst + i * 16) = *reinterpret_cast<const u32x4*>(srcp + i * 16);
    }
  }
#undef STAGE
}

// ---------------- kernel 2: fused stat-combine + reduce + epilogue ----------------
__global__ __launch_bounds__(256) void k_out(const unsigned short* __restrict__ part_o,
                                             const float* __restrict__ part_m,
                                             const float* __restrict__ part_l,
                                             const float* __restrict__ v,
                                             const float* __restrict__ mask,
                                             float* __restrict__ out) {
  int b = blockIdx.x, t = threadIdx.x;
  __shared__ float sc[NSPLIT];
  __shared__ float red[8];
  float m = -__builtin_inff(), l = 0.f;
  if (t < NSPLIT) {
    m = part_m[(size_t)b * NSPLIT + t];
    l = part_l[(size_t)b * NSPLIT + t];
  }
  float mm = m;
#pragma unroll
  for (int s2 = 32; s2; s2 >>= 1) mm = fmaxf(mm, __shfl_xor(mm, s2));
  if ((t & 63) == 0) red[t >> 6] = mm;
  __syncthreads();
  float M = fmaxf(red[0], red[1]);
  float e = (t < NSPLIT) ? __expf(m - M) : 0.f;
  float z = e * l;
#pragma unroll
  for (int s2 = 32; s2; s2 >>= 1) z += __shfl_xor(z, s2);
  if ((t & 63) == 0) red[4 + (t >> 6)] = z;
  __syncthreads();
  float Z = red[4] + red[5];
  if (t < NSPLIT) sc[t] = e / Z;
  __syncthreads();

  float a = 0.f;
  const unsigned short* po = part_o + (size_t)b * 256 + t;
#pragma unroll 8
  for (int gi = 0; gi < NSPLIT; ++gi)
    a = fmaf(sc[gi], bf2f(po[(size_t)gi * 131072]), a);
  size_t idx = (size_t)b * 256 + t;
  float vv = v[idx], mk = mask[idx];
  out[idx] = vv + 0.5f * (a - vv) * mk;
}

extern "C" void kernel_launch(void* const* d_in, const int* in_sizes, int n_in,
                              void* d_out, int out_size, void* d_ws, size_t ws_size,
                              hipStream_t stream) {
  const float* v = (const float*)d_in[0];       // [512,256]
  const float* mask = (const float*)d_in[1];    // [512,256]
  const float* memg = (const float*)d_in[2];    // [65536,256]
  float* out = (float*)d_out;

  char* ws = (char*)d_ws;
  const size_t SZ_PO = (size_t)NSPLIT * B_DIM * D_DIM * 2;   // 32 MiB
  const size_t SZ_MA = (size_t)M_TOT * D_DIM * 2;            // 32 MiB
  const size_t SZ_MS = (size_t)M_TOT * 4;                    // 256 KiB
  const size_t SZ_VB = (size_t)B_DIM * D_DIM * 2;            // 256 KiB
  const size_t SZ_ST = (size_t)B_DIM * NSPLIT * 4;           // 256 KiB
  unsigned short* part_o = (unsigned short*)ws;
  unsigned short* memA = (unsigned short*)(ws + SZ_PO);
  float* msq = (float*)(ws + SZ_PO + SZ_MA);
  unsigned short* vbf = (unsigned short*)(ws + SZ_PO + SZ_MA + SZ_MS);
  float* part_m = (float*)(ws + SZ_PO + SZ_MA + SZ_MS + SZ_VB);
  float* part_l = (float*)(ws + SZ_PO + SZ_MA + SZ_MS + SZ_VB + SZ_ST);

  k_prep<<<dim3(272), dim3(512), 0, stream>>>(memg, v, memA, vbf, msq);
  k_stage1<<<dim3(256), dim3(512), 0, stream>>>(memA, vbf, msq, part_o, part_m, part_l);
  k_out<<<dim3(B_DIM), dim3(256), 0, stream>>>(part_o, part_m, part_l, v, mask, out);
}

// Round 5
// 117.076 us; speedup vs baseline: 2.1688x; 2.1688x over previous
//
#include <hip/hip_runtime.h>
#include <hip/hip_bf16.h>

// out = v + 0.5*mask*(softmax_m(mem@v^T - 0.5*||mem||^2)^T @ mem - v)
//  k_prep  : memories f32 -> bf16 (memA) + row sumsq (msq); v -> bf16 (vbf)
//  k_stage1: 512 WGs (256 thr, 4 waves) = 128 m-splits x 4 b-tiles.
//            16 chunks of 32 m, dbuf global_load_lds A staging, in-LDS
//            transpose -> padded Tb, 32 b per wave (2 col frags), defer-max
//            online softmax, PV acc in [d][b] orientation (lane-uniform
//            rescale). __launch_bounds__(256,2) -> 256-VGPR cap, no spill.
//  k_out   : fused stat combine + partial reduction + epilogue

#define D_DIM 256
#define B_DIM 512
#define M_TOT 65536
#define NSPLIT 128     // m-splits; 512 m per split
#define CHUNK 32
#define NCHUNK 16

typedef __attribute__((ext_vector_type(4))) float f32x4;
typedef __attribute__((ext_vector_type(2))) float f32x2;
typedef __attribute__((ext_vector_type(8))) short s16x8;
typedef __attribute__((ext_vector_type(2))) unsigned int u32x2;
typedef __attribute__((ext_vector_type(4))) unsigned int u32x4;

__device__ __forceinline__ unsigned short bf16rn(float f) {
  unsigned x = __builtin_bit_cast(unsigned, f);
  x += 0x7fffu + ((x >> 16) & 1u);
  return (unsigned short)(x >> 16);
}
__device__ __forceinline__ unsigned pk2(float a, float b) {
  return (unsigned)bf16rn(a) | ((unsigned)bf16rn(b) << 16);
}
__device__ __forceinline__ float bf2f(unsigned short u) {
  return __builtin_bit_cast(float, ((unsigned)u) << 16);
}

// Tb swizzle (rows padded to 128B): spreads transpose-writes and PV reads.
#define TSWZ(d) ((((d) ^ ((d) >> 3)) & 7) << 4)

// ---------------- kernel 0: prep ----------------
__global__ __launch_bounds__(512) void k_prep(const float* __restrict__ memg,
                                              const float* __restrict__ v,
                                              unsigned short* __restrict__ memA,
                                              unsigned short* __restrict__ vbf,
                                              float* __restrict__ msq) {
  const int wg = (int)blockIdx.x;
  const int tid = (int)threadIdx.x;
  const int w = tid >> 6, lane = tid & 63;
  if (wg < 256) {
    size_t m0 = (size_t)wg * 256 + w * 32;
#pragma unroll 4
    for (int i = 0; i < 32; ++i) {
      size_t m = m0 + i;
      f32x4 f = *reinterpret_cast<const f32x4*>(memg + m * 256 + lane * 4);
      u32x2 p;
      p[0] = pk2(f[0], f[1]);
      p[1] = pk2(f[2], f[3]);
      *reinterpret_cast<u32x2*>(memA + m * 256 + lane * 4) = p;
      float sq = f[0] * f[0] + f[1] * f[1] + f[2] * f[2] + f[3] * f[3];
#pragma unroll
      for (int s2 = 32; s2; s2 >>= 1) sq += __shfl_xor(sq, s2);
      if (lane == 0) msq[m] = sq;
    }
  } else {
    size_t base = (size_t)(wg - 256) * 8192 + (size_t)tid * 16;
#pragma unroll
    for (int i = 0; i < 4; ++i) {
      f32x4 f = *reinterpret_cast<const f32x4*>(v + base + i * 4);
      u32x2 p;
      p[0] = pk2(f[0], f[1]);
      p[1] = pk2(f[2], f[3]);
      *reinterpret_cast<u32x2*>(vbf + base + i * 4) = p;
    }
  }
}

// ---------------- softmax + PA macros (CHUNK=32: S_[2] f32x4) ----------------
#define SOFTMAX_UPD(S_, rm_, rs_, acc_)                                        \
  {                                                                            \
    float mx = S_[0][0];                                                       \
    _Pragma("unroll") for (int rf_ = 0; rf_ < 2; ++rf_)                        \
        _Pragma("unroll") for (int r_ = 0; r_ < 4; ++r_)                       \
            mx = fmaxf(mx, S_[rf_][r_]);                                       \
    mx = fmaxf(mx, __shfl_xor(mx, 16));                                        \
    mx = fmaxf(mx, __shfl_xor(mx, 32));                                        \
    if (!__all(mx <= rm_ + 8.0f)) {                                            \
      float nm = fmaxf(rm_, mx);                                               \
      float al = __expf(rm_ - nm);                                             \
      rm_ = nm;                                                                \
      rs_ *= al;                                                               \
      _Pragma("unroll") for (int n_ = 0; n_ < 16; ++n_) acc_[n_] = acc_[n_] * al; \
    }                                                                          \
    float ls = 0.f;                                                            \
    _Pragma("unroll") for (int rf_ = 0; rf_ < 2; ++rf_)                        \
        _Pragma("unroll") for (int r_ = 0; r_ < 4; ++r_) {                     \
      float p_ = __expf(S_[rf_][r_] - rm_);                                    \
      S_[rf_][r_] = p_;                                                        \
      ls += p_;                                                                \
    }                                                                          \
    ls += __shfl_xor(ls, 16);                                                  \
    ls += __shfl_xor(ls, 32);                                                  \
    rs_ += ls;                                                                 \
  }

#define MAKE_PA(S_, pa_)                                                       \
  {                                                                            \
    unsigned q00 = pk2(S_[0][0], S_[0][1]);                                    \
    unsigned q01 = pk2(S_[0][2], S_[0][3]);                                    \
    unsigned q10 = pk2(S_[1][0], S_[1][1]);                                    \
    unsigned q11 = pk2(S_[1][2], S_[1][3]);                                    \
    int srcA = ((lane & 16) >> 3) * 16 + c;                                    \
    int srcB = srcA + 16;                                                      \
    unsigned a0 = (unsigned)__shfl((int)q00, srcA);                            \
    unsigned b0 = (unsigned)__shfl((int)q10, srcA);                            \
    unsigned a1 = (unsigned)__shfl((int)q01, srcA);                            \
    unsigned b1 = (unsigned)__shfl((int)q11, srcA);                            \
    unsigned a2 = (unsigned)__shfl((int)q00, srcB);                            \
    unsigned b2 = (unsigned)__shfl((int)q10, srcB);                            \
    unsigned a3 = (unsigned)__shfl((int)q01, srcB);                            \
    unsigned b3 = (unsigned)__shfl((int)q11, srcB);                            \
    bool hi = lane >= 32;                                                      \
    u32x4 wv;                                                                  \
    wv[0] = hi ? b0 : a0;                                                      \
    wv[1] = hi ? b1 : a1;                                                      \
    wv[2] = hi ? b2 : a2;                                                      \
    wv[3] = hi ? b3 : a3;                                                      \
    pa_ = __builtin_bit_cast(s16x8, wv);                                       \
  }

// ---------------- kernel 1: split-M flash ----------------
__global__ __launch_bounds__(256, 2) void k_stage1(
    const unsigned short* __restrict__ memA, const unsigned short* __restrict__ vbf,
    const float* __restrict__ msq, unsigned short* __restrict__ part_o,
    float* __restrict__ part_m, float* __restrict__ part_l) {
  __shared__ __align__(16) char lds[65536];  // Ab0 16K | Ab1 16K | Tb 32K (padded rows)
  char* const Ab0 = lds;
  char* const Ab1 = lds + 16384;
  char* const Tb = lds + 32768;

  const int tid = (int)threadIdx.x;
  const int w = tid >> 6;
  const int lane = tid & 63;
  const int g = lane >> 4;
  const int c = lane & 15;

  // XCD grouping: 4 b-tiles of an m-split on one XCD; 16 splits per XCD.
  const int bid = (int)blockIdx.x;
  const int xcd = bid & 7, j = bid >> 3;
  const int s = xcd * 16 + (j >> 2);   // m-split 0..127
  const int btile = j & 3;             // b-tile 0..3
  const int mbase = s * 512;
  const int bw = btile * 128 + w * 32;

  // staging source (inverse-swizzled global addr; LDS dest linear)
  const char* memAc = (const char*)memA;
  const size_t a_src0 = ((size_t)mbase + (size_t)(tid >> 5)) * 512 +
                        (size_t)((((tid & 31) ^ (tid >> 5))) * 16);

#define STAGE(bufp, t)                                                          \
  do {                                                                          \
    _Pragma("unroll") for (int i_ = 0; i_ < 4; ++i_) {                          \
      __builtin_amdgcn_global_load_lds(                                         \
          (const __attribute__((address_space(1))) void*)(memAc + a_src0 +      \
              (size_t)(t) * 16384 + (size_t)i_ * 4096),                         \
          (__attribute__((address_space(3))) void*)((bufp) + i_ * 4096 + w * 1024), \
          16, 0, 0);                                                            \
    }                                                                           \
  } while (0)

  f32x4 acc0[16], acc1[16];
#pragma unroll
  for (int n = 0; n < 16; ++n) { acc0[n] = (f32x4)0.0f; acc1[n] = (f32x4)0.0f; }
  float rm0 = -__builtin_inff(), rs0 = 0.f;
  float rm1 = -__builtin_inff(), rs1 = 0.f;

  s16x8 vr0[8], vr1[8];

  STAGE(Ab0, 0);
#pragma unroll
  for (int k = 0; k < 8; ++k) {
    vr0[k] = *reinterpret_cast<const s16x8*>(vbf + (size_t)(bw + c) * 256 + k * 32 + g * 8);
    vr1[k] = *reinterpret_cast<const s16x8*>(vbf + (size_t)(bw + 16 + c) * 256 + k * 32 + g * 8);
  }

  asm volatile("s_waitcnt vmcnt(0)" ::: "memory");
  __builtin_amdgcn_s_barrier();
  asm volatile("" ::: "memory");

  // transpose thread mapping: mb = tid&7 (4 m each), db = tid>>3 (8 d each)
  const int mb = tid & 7;
  const int db = tid >> 3;

  for (int t = 0; t < NCHUNK; ++t) {
    char* Abc = (t & 1) ? Ab1 : Ab0;
    char* Abn = (t & 1) ? Ab0 : Ab1;
    if (t < NCHUNK - 1) STAGE(Abn, t + 1);

    // ---- transpose Ab[cur] -> Tb (4 b128 reads, 8 b64 swizzled writes) ----
    {
      u32x4 r0 = *reinterpret_cast<const u32x4*>(Abc + (mb * 4 + 0) * 512 + ((db * 16) ^ (((mb * 4 + 0) & 7) << 4)));
      u32x4 r1 = *reinterpret_cast<const u32x4*>(Abc + (mb * 4 + 1) * 512 + ((db * 16) ^ (((mb * 4 + 1) & 7) << 4)));
      u32x4 r2 = *reinterpret_cast<const u32x4*>(Abc + (mb * 4 + 2) * 512 + ((db * 16) ^ (((mb * 4 + 2) & 7) << 4)));
      u32x4 r3 = *reinterpret_cast<const u32x4*>(Abc + (mb * 4 + 3) * 512 + ((db * 16) ^ (((mb * 4 + 3) & 7) << 4)));
#pragma unroll
      for (int dd = 0; dd < 8; ++dd) {
        int sh = (dd & 1) * 16;
        unsigned h0 = (r0[dd >> 1] >> sh) & 0xffffu;
        unsigned h1 = (r1[dd >> 1] >> sh) & 0xffffu;
        unsigned h2 = (r2[dd >> 1] >> sh) & 0xffffu;
        unsigned h3 = (r3[dd >> 1] >> sh) & 0xffffu;
        u32x2 pw;
        pw[0] = h0 | (h1 << 16);
        pw[1] = h2 | (h3 << 16);
        int d = db * 8 + dd;
        *reinterpret_cast<u32x2*>(Tb + ((d * 128 + mb * 8) ^ TSWZ(d))) = pw;
      }
    }
    asm volatile("s_waitcnt lgkmcnt(0)" ::: "memory");
    __builtin_amdgcn_s_barrier();
    asm volatile("" ::: "memory");

    const int mc = mbase + t * CHUNK;

    // ---- QK^T (swapped): S[rf=2 m-frags][b=c], two column-fragments ----
    f32x4 S0[2], S1[2];
#pragma unroll
    for (int rf = 0; rf < 2; ++rf) { S0[rf] = (f32x4)0.0f; S1[rf] = (f32x4)0.0f; }
    __builtin_amdgcn_s_setprio(1);
#pragma unroll
    for (int k = 0; k < 8; ++k) {
#pragma unroll
      for (int rf = 0; rf < 2; ++rf) {
        s16x8 a = *reinterpret_cast<const s16x8*>(
            Abc + (rf * 16 + c) * 512 + ((k * 64 + g * 16) ^ ((c & 7) << 4)));
        S0[rf] = __builtin_amdgcn_mfma_f32_16x16x32_bf16(a, vr0[k], S0[rf], 0, 0, 0);
        S1[rf] = __builtin_amdgcn_mfma_f32_16x16x32_bf16(a, vr1[k], S1[rf], 0, 0, 0);
      }
    }
    __builtin_amdgcn_s_setprio(0);
    // bias: row m = rf*16 + 4g + r
#pragma unroll
    for (int rf = 0; rf < 2; ++rf) {
      f32x4 q = *reinterpret_cast<const f32x4*>(msq + mc + rf * 16 + g * 4);
#pragma unroll
      for (int r = 0; r < 4; ++r) { S0[rf][r] -= 0.5f * q[r]; S1[rf][r] -= 0.5f * q[r]; }
    }

    // ---- online softmax (lane-uniform rescale) ----
    SOFTMAX_UPD(S0, rm0, rs0, acc0);
    SOFTMAX_UPD(S1, rm1, rs1, acc1);

    // ---- PV: acc[d][b] += memT @ P ----
    {
      s16x8 pa0, pa1;
      MAKE_PA(S0, pa0);
      MAKE_PA(S1, pa1);
      __builtin_amdgcn_s_setprio(1);
#pragma unroll
      for (int n = 0; n < 16; ++n) {
        int d = n * 16 + c;
        s16x8 bm = *reinterpret_cast<const s16x8*>(Tb + ((d * 128 + g * 16) ^ TSWZ(d)));
        acc0[n] = __builtin_amdgcn_mfma_f32_16x16x32_bf16(bm, pa0, acc0[n], 0, 0, 0);
        acc1[n] = __builtin_amdgcn_mfma_f32_16x16x32_bf16(bm, pa1, acc1[n], 0, 0, 0);
      }
      __builtin_amdgcn_s_setprio(0);
    }

    asm volatile("s_waitcnt vmcnt(0)" ::: "memory");
    __builtin_amdgcn_s_barrier();
    asm volatile("" ::: "memory");
  }

  // ---- stats: b = bw + cf*16 + c ----
  if (g == 0) {
    int b0s = bw + c;
    part_m[(size_t)b0s * NSPLIT + s] = rm0;
    part_l[(size_t)b0s * NSPLIT + s] = rs0;
    part_m[(size_t)(b0s + 16) * NSPLIT + s] = rm1;
    part_l[(size_t)(b0s + 16) * NSPLIT + s] = rs1;
  }

  // ---- epilogue: acc lane layout (d = n*16+4g+r, b = bw+cf*16+c) ----
  {
    char* ep = lds;
#pragma unroll
    for (int cf = 0; cf < 2; ++cf) {
      __syncthreads();
#pragma unroll
      for (int n = 0; n < 16; ++n) {
        u32x2 pw;
        if (cf == 0) { pw[0] = pk2(acc0[n][0], acc0[n][1]); pw[1] = pk2(acc0[n][2], acc0[n][3]); }
        else         { pw[0] = pk2(acc1[n][0], acc1[n][1]); pw[1] = pk2(acc1[n][2], acc1[n][3]); }
        *reinterpret_cast<u32x2*>(ep + w * 8448 + c * 528 + (n * 16 + 4 * g) * 2) = pw;
      }
      __syncthreads();
      int row = tid >> 2, q = tid & 3;
      size_t bglob = (size_t)btile * 128 + (size_t)(row >> 4) * 32 + (size_t)cf * 16 + (row & 15);
      char* dst = (char*)part_o + ((size_t)s * 512 + bglob) * 512 + q * 128;
      const char* srcp = ep + (row >> 4) * 8448 + (row & 15) * 528 + q * 128;
#pragma unroll
      for (int i = 0; i < 8; ++i)
        *reinterpret_cast<u32x4*>(dst + i * 16) = *reinterpret_cast<const u32x4*>(srcp + i * 16);
    }
  }
#undef STAGE
}

// ---------------- kernel 2: fused stat-combine + reduce + epilogue ----------------
__global__ __launch_bounds__(128) void k_out(const unsigned short* __restrict__ part_o,
                                             const float* __restrict__ part_m,
                                             const float* __restrict__ part_l,
                                             const float* __restrict__ v,
                                             const float* __restrict__ mask,
                                             float* __restrict__ out) {
  int b = blockIdx.x, t = threadIdx.x;
  int wv = t >> 6;
  __shared__ float sc[NSPLIT];
  __shared__ float red[4];
  float m = part_m[(size_t)b * NSPLIT + t];
  float l = part_l[(size_t)b * NSPLIT + t];
  float mm = m;
#pragma unroll
  for (int s2 = 32; s2; s2 >>= 1) mm = fmaxf(mm, __shfl_xor(mm, s2));
  if ((t & 63) == 0) red[wv] = mm;
  __syncthreads();
  float M = fmaxf(red[0], red[1]);
  float e = __expf(m - M);
  float z = e * l;
#pragma unroll
  for (int s2 = 32; s2; s2 >>= 1) z += __shfl_xor(z, s2);
  if ((t & 63) == 0) red[2 + wv] = z;
  __syncthreads();
  float Z = red[2] + red[3];
  sc[t] = e / Z;
  __syncthreads();

  float a0 = 0.f, a1 = 0.f;
  const unsigned short* po = part_o + (size_t)b * 256 + 2 * t;
#pragma unroll 8
  for (int gi = 0; gi < NSPLIT; ++gi) {
    unsigned u = *reinterpret_cast<const unsigned*>(po + (size_t)gi * 131072);
    a0 = fmaf(sc[gi], bf2f((unsigned short)u), a0);
    a1 = fmaf(sc[gi], bf2f((unsigned short)(u >> 16)), a1);
  }
  size_t idx = (size_t)b * 256 + 2 * t;
  f32x2 vv = *reinterpret_cast<const f32x2*>(v + idx);
  f32x2 mk = *reinterpret_cast<const f32x2*>(mask + idx);
  out[idx] = vv[0] + 0.5f * (a0 - vv[0]) * mk[0];
  out[idx + 1] = vv[1] + 0.5f * (a1 - vv[1]) * mk[1];
}

extern "C" void kernel_launch(void* const* d_in, const int* in_sizes, int n_in,
                              void* d_out, int out_size, void* d_ws, size_t ws_size,
                              hipStream_t stream) {
  const float* v = (const float*)d_in[0];       // [512,256]
  const float* mask = (const float*)d_in[1];    // [512,256]
  const float* memg = (const float*)d_in[2];    // [65536,256]
  float* out = (float*)d_out;

  char* ws = (char*)d_ws;
  const size_t SZ_PO = (size_t)NSPLIT * B_DIM * D_DIM * 2;   // 32 MiB
  const size_t SZ_MA = (size_t)M_TOT * D_DIM * 2;            // 32 MiB
  const size_t SZ_MS = (size_t)M_TOT * 4;                    // 256 KiB
  const size_t SZ_VB = (size_t)B_DIM * D_DIM * 2;            // 256 KiB
  const size_t SZ_ST = (size_t)B_DIM * NSPLIT * 4;           // 256 KiB
  unsigned short* part_o = (unsigned short*)ws;
  unsigned short* memA = (unsigned short*)(ws + SZ_PO);
  float* msq = (float*)(ws + SZ_PO + SZ_MA);
  unsigned short* vbf = (unsigned short*)(ws + SZ_PO + SZ_MA + SZ_MS);
  float* part_m = (float*)(ws + SZ_PO + SZ_MA + SZ_MS + SZ_VB);
  float* part_l = (float*)(ws + SZ_PO + SZ_MA + SZ_MS + SZ_VB + SZ_ST);

  k_prep<<<dim3(272), dim3(512), 0, stream>>>(memg, v, memA, vbf, msq);
  k_stage1<<<dim3(512), dim3(256), 0, stream>>>(memA, vbf, msq, part_o, part_m, part_l);
  k_out<<<dim3(B_DIM), dim3(128), 0, stream>>>(part_o, part_m, part_l, v, mask, out);
}